// Round 2
// 157.769 us; speedup vs baseline: 1.0261x; 1.0261x over previous
//
#include <hip/hip_runtime.h>
#include <math.h>

typedef _Float16 f16;
typedef _Float16 f16x8 __attribute__((ext_vector_type(8)));
typedef float f32x16 __attribute__((ext_vector_type(16)));

#define MFMA_ __builtin_amdgcn_mfma_f32_32x32x16_f16
#define SLOPE_ 0.2f

constexpr int kB = 64, kT = 512, kD = 8, kH = 128, kE = 96;
constexpr int kFG = 145, kTM = 510, kN = kB * kTM;   // 32640 = 255*128

// k-permutation absorbed into weight images so next-layer B-fragments are the
// held C/D quads verbatim: pi(16c+8s+j) = 32(c>>1)+16(c&1)+8(j>>2)+4s+(j&3)
__device__ __forceinline__ int pif(int k) {
  if (k >= 128) return k;
  int c = k >> 4, s = (k >> 3) & 1, j = k & 7;
  return ((c >> 1) << 5) | ((c & 1) << 4) | ((j >> 2) << 3) | (s << 2) | (j & 3);
}

// fragment-linear images: frag f = 64 lanes x 16 B contiguous.
__device__ __forceinline__ f16x8 gfrag(const f16* img, int f, int lane) {
  return *(const f16x8*)(img + (size_t)f*512 + lane*8);
}

// async global->LDS DMA, 16B per lane. LDS dest = wave-uniform base + lane*16
// (linear lane-order layout required and satisfied here).
__device__ __forceinline__ void lds_dma16(const f16* g, f16* l) {
  __builtin_amdgcn_global_load_lds(
      (const __attribute__((address_space(1))) void*)g,
      (__attribute__((address_space(3))) void*)l, 16, 0, 0);
}

// ========= weight pre-convert: f32 row-major -> f16 fragment-linear =========
template<int NF, int SK, int PERM>
__device__ __forceinline__ void cvt_img(const float* __restrict__ src,
                                        f16* __restrict__ dst, int nd,
                                        int t0, int stride) {
  const int per_d = NF * 512;
  for (int e = t0; e < nd * per_d; e += stride) {
    int dd = e / per_d, r = e - dd * per_d;
    int f = r >> 9, l = (r >> 3) & 63, j = r & 7;
    int c = f >> 2, t = f & 3;
    int row = t*32 + (l & 31);
    int col = c*16 + ((l >> 5) << 3) + j;
    if (PERM) col = pif(col);
    dst[e] = (f16)src[((size_t)dd*kH + row)*SK + col];
  }
}

__global__ __launch_bounds__(256) void cvt_kernel(
    const float* __restrict__ gW0, const float* __restrict__ gW1,
    const float* __restrict__ gW2,
    const float* __restrict__ gb0, const float* __restrict__ gb1,
    const float* __restrict__ gb2, const float* __restrict__ gWf,
    const float* __restrict__ fcW0, const float* __restrict__ fcW1,
    const float* __restrict__ fcWf,
    f16* __restrict__ W0img, f16* __restrict__ W1img, f16* __restrict__ W2img,
    f16* __restrict__ wfimg,
    f16* __restrict__ fW0img, f16* __restrict__ fW1img, f16* __restrict__ fWfimg,
    float* __restrict__ w144buf, float* __restrict__ logdet)
{
  const int stride = gridDim.x * 256;
  const int t0 = blockIdx.x*256 + threadIdx.x;

  // W0img: 40 frags/d. cols: 0..127 pi(gW0), 128..144 canonical gW0 (incl w144),
  // 145 = gb0, 146..159 = 0.
  for (int e = t0; e < kD*40*512; e += stride) {
    int dd = e / (40*512), r = e - dd*(40*512);
    int f = r >> 9, l = (r >> 3) & 63, j = r & 7;
    int c = f >> 2, t = f & 3;
    int row = t*32 + (l & 31);
    int col = c*16 + ((l >> 5) << 3) + j;
    float v;
    if (col < 128)      v = gW0[((size_t)dd*kH + row)*kFG + pif(col)];
    else if (col < 145) v = gW0[((size_t)dd*kH + row)*kFG + col];
    else if (col == 145) v = gb0[dd*kH + row];
    else                v = 0.f;
    W0img[e] = (f16)v;
  }
  // W1img/W2img: 36 frags/d. cols 0..127 pi(W), col 128 = bias, 129..143 = 0.
  for (int e = t0; e < kD*36*512; e += stride) {
    int dd = e / (36*512), r = e - dd*(36*512);
    int f = r >> 9, l = (r >> 3) & 63, j = r & 7;
    int c = f >> 2, t = f & 3;
    int row = t*32 + (l & 31);
    int col = c*16 + ((l >> 5) << 3) + j;
    float v1, v2;
    if (col < 128) {
      int pc = pif(col);
      v1 = gW1[((size_t)dd*kH + row)*kH + pc];
      v2 = gW2[((size_t)dd*kH + row)*kH + pc];
    } else if (col == 128) {
      v1 = gb1[dd*kH + row];
      v2 = gb2[dd*kH + row];
    } else { v1 = 0.f; v2 = 0.f; }
    W1img[e] = (f16)v1;
    W2img[e] = (f16)v2;
  }
  // wfimg: 8 frags/d, wf in output-row 0 only, pi-ordered cols.
  for (int e = t0; e < kD*8*512; e += stride) {
    int dd = e >> 12, r = e & 4095;
    int f = r >> 9, l = (r >> 3) & 63, j = r & 7;
    int row = l & 31;
    int col = f*16 + ((l >> 5) << 3) + j;
    wfimg[e] = (f16)((row == 0) ? gWf[dd*kH + pif(col)] : 0.f);
  }
  cvt_img<24, kE , 0>(fcW0, fW0img, 1, t0, stride);
  cvt_img<32, kH , 1>(fcW1, fW1img, 1, t0, stride);
  cvt_img<32, kH , 1>(fcWf, fWfimg, 1, t0, stride);
  for (int i = t0; i < kD*kH; i += stride)
    w144buf[i] = gW0[(size_t)i*kFG + 144];
  if (t0 < kB) logdet[t0] = 0.f;
}

// ===== fc_mlp: emb(N,96) -> embh'(N,128) f16 (pi-ordered); 1 barrier ========
__global__ __launch_bounds__(256, 2) void fc_kernel(
    const float* __restrict__ emb,
    const f16* __restrict__ fW0, const f16* __restrict__ fW1,
    const f16* __restrict__ fWf,
    const float* __restrict__ b0, const float* __restrict__ b1,
    const float* __restrict__ bf, f16* __restrict__ out)
{
  __shared__ f16 wbuf[62*512];                 // fW1 frags 0..31, fWf frags 0..29
  const int bn = blockIdx.x * 128;
  const int tid = threadIdx.x, wave = tid >> 6, lane = tid & 63;
  const int l31 = lane & 31, h5 = lane >> 5;
  const int wbase = wave << 6;
  const int n = bn + wave*32 + l31;

  // stage via LDS-DMA: no VGPR round-trip, no staging address VALU
  #pragma unroll
  for (int i = 0; i < 8; ++i)
    lds_dma16(fW1 + (size_t)(i*256 + tid)*8, wbuf + (size_t)(i*256 + wbase)*8);
  #pragma unroll
  for (int i = 0; i < 8; ++i) {
    int idx = i*256 + tid;
    if (idx < 1920)   // wave-uniform: 1920 = 7*256 + 128 (wave boundary)
      lds_dma16(fWf + (size_t)idx*8, wbuf + (size_t)(2048 + i*256 + wbase)*8);
  }

  const float* erow = emb + (size_t)n*kE + h5*8;
  f16x8 eB[6];
  #pragma unroll
  for (int c = 0; c < 6; ++c) {
    float4 a = *(const float4*)(erow + c*16);
    float4 bb = *(const float4*)(erow + c*16 + 4);
    f16x8 v;
    v[0]=(f16)a.x; v[1]=(f16)a.y; v[2]=(f16)a.z; v[3]=(f16)a.w;
    v[4]=(f16)bb.x; v[5]=(f16)bb.y; v[6]=(f16)bb.z; v[7]=(f16)bb.w;
    eB[c] = v;
  }
  __syncthreads();                              // B1: wbuf ready

  f32x16 zero = {};
  f32x16 acc[4] = {zero, zero, zero, zero};
  // triple-buffered global A-fragments: prefetch c+2 while computing c
  f16x8 wpre[3][4];
  #pragma unroll
  for (int t = 0; t < 4; ++t) wpre[0][t] = gfrag(fW0, t, lane);
  #pragma unroll
  for (int t = 0; t < 4; ++t) wpre[1][t] = gfrag(fW0, 4+t, lane);
  #pragma unroll
  for (int c = 0; c < 6; ++c) {
    if (c + 2 < 6)
      #pragma unroll
      for (int t = 0; t < 4; ++t) wpre[(c+2)%3][t] = gfrag(fW0, (c+2)*4+t, lane);
    #pragma unroll
    for (int t = 0; t < 4; ++t)
      acc[t] = MFMA_(wpre[c%3][t], eB[c], acc[t], 0, 0, 0);
  }

  f16x8 hq[4][2];
  #pragma unroll
  for (int t = 0; t < 4; ++t)
    #pragma unroll
    for (int q = 0; q < 4; ++q) {
      float4 b4 = *(const float4*)(b0 + t*32 + q*8 + h5*4);
      const float* bp = (const float*)&b4;
      #pragma unroll
      for (int e = 0; e < 4; ++e) {
        float z = acc[t][q*4+e] + bp[e];
        hq[t][q>>1][(q&1)*4+e] = (f16)fmaxf(z, SLOPE_*z);
      }
    }

  #pragma unroll
  for (int t = 0; t < 4; ++t) acc[t] = zero;
  #pragma unroll
  for (int c = 0; c < 8; ++c) {
    f16x8 bP = hq[c>>1][c&1];
    #pragma unroll
    for (int t = 0; t < 4; ++t)
      acc[t] = MFMA_(*(const f16x8*)(wbuf + (size_t)(c*4+t)*512 + lane*8),
                     bP, acc[t], 0, 0, 0);
  }
  #pragma unroll
  for (int t = 0; t < 4; ++t)
    #pragma unroll
    for (int q = 0; q < 4; ++q) {
      float4 b4 = *(const float4*)(b1 + t*32 + q*8 + h5*4);
      const float* bp = (const float*)&b4;
      #pragma unroll
      for (int e = 0; e < 4; ++e) {
        float z = acc[t][q*4+e] + bp[e];
        hq[t][q>>1][(q&1)*4+e] = (f16)fmaxf(z, SLOPE_*z);
      }
    }

  #pragma unroll
  for (int t = 0; t < 4; ++t) acc[t] = zero;
  #pragma unroll
  for (int c = 0; c < 8; ++c) {
    f16x8 bP = hq[c>>1][c&1];
    #pragma unroll
    for (int t = 0; t < 4; ++t) {
      int f = c*4 + t;
      f16x8 a = (f < 30) ? *(const f16x8*)(wbuf + (size_t)(32 + f)*512 + lane*8)
                         : gfrag(fWf, f, lane);
      acc[t] = MFMA_(a, bP, acc[t], 0, 0, 0);
    }
  }
  #pragma unroll
  for (int t = 0; t < 4; ++t)
    #pragma unroll
    for (int q = 0; q < 4; ++q) {
      float4 b4 = *(const float4*)(bf + t*32 + q*8 + h5*4);
      const float* bp = (const float*)&b4;
      #pragma unroll
      for (int e = 0; e < 4; ++e)
        hq[t][q>>1][(q&1)*4+e] = (f16)(acc[t][q*4+e] + bp[e]);
    }
  #pragma unroll
  for (int c = 0; c < 8; ++c)
    *(f16x8*)(out + (size_t)n*kH + c*16 + h5*8) = hq[c>>1][c&1];
}

// ==== g_mlp fwd + JVP: R6 structure + load pipelining =======================
// Block = 128 rows x one d, 4 waves x 32 rows x all cols. 2 waves/SIMD by
// design (128 VGPR + 128 AGPR); W1+W2 staged via LDS-DMA in 72 KB; 2 barriers.
// All global B/A operands for L0 and the final dot are preloaded/pipelined so
// the per-chunk load-use latency (embh: HBM/L3 ~500-900cy, W0/WF frags: L2
// ~200cy) is issued once, not 10x serially.
__global__ __launch_bounds__(256, 2) void g_kernel(
    const float* __restrict__ x, const f16* __restrict__ embh,
    const f16* __restrict__ W0img, const f16* __restrict__ W1img,
    const f16* __restrict__ W2img, const f16* __restrict__ wfimg,
    const float* __restrict__ w144buf, const float* __restrict__ gbf,
    float* __restrict__ resid, float* __restrict__ logdet)
{
  __shared__ f16 wbuf[72*512];                 // W1 frags 0..35, W2 frags 36..71
  __shared__ float part[8];
  const int d = blockIdx.y, bx = blockIdx.x, bn = bx*128;
  const int tid = threadIdx.x, wave = tid >> 6, lane = tid & 63;
  const int l31 = lane & 31, h5 = lane >> 5;
  const int wbase = wave << 6;
  const int n = bn + wave*32 + l31;
  const int b = n / kTM, tt = n - b*kTM;

  const f16* W0d = W0img + (size_t)d*40*512;
  const f16* W1d = W1img + (size_t)d*36*512;
  const f16* W2d = W2img + (size_t)d*36*512;
  const f16* WFd = wfimg + (size_t)d*8*512;

  // ---- stage W1 + W2 via LDS-DMA (linear lane-order layout; frees ~72 VGPR
  // of in-flight staging pressure so the L0 preloads below fit in registers)
  #pragma unroll
  for (int i = 0; i < 9; ++i)
    lds_dma16(W1d + (size_t)(i*256 + tid)*8, wbuf + (size_t)(i*256 + wbase)*8);
  #pragma unroll
  for (int i = 0; i < 9; ++i)
    lds_dma16(W2d + (size_t)(i*256 + tid)*8,
              wbuf + (size_t)(36*512) + (size_t)(i*256 + wbase)*8);

  // x-derived inputs
  const float* xp = x + ((size_t)b*kT + tt + h5)*kD;
  float4 xa = *(const float4*)xp;
  float4 xb = *(const float4*)(xp + 4);
  f16x8 f8;
  f8[0]=(f16)xa.x; f8[1]=(f16)xa.y; f8[2]=(f16)xa.z; f8[3]=(f16)xa.w;
  f8[4]=(f16)xb.x; f8[5]=(f16)xb.y; f8[6]=(f16)xb.z; f8[7]=(f16)xb.w;
  const float xxv = x[((size_t)b*kT + tt + 2)*kD + d];
  f16x8 zeroh = {};
  f16x8 xb9 = zeroh;                 // chunk 9: [xx, 1, 0...] on h5==0 lanes
  if (!h5) { xb9[0] = (f16)xxv; xb9[1] = (f16)1.f; }
  f16x8 bC = zeroh;                  // bias chunk: [1, 0...] on h5==0 lanes
  if (!h5) bC[0] = (f16)1.f;

  // ---- preload ALL 10 B-operand chunks before the chain (embh is the
  // long-latency read; hq arrays are dead here so this fits the reg budget)
  const f16* erow = embh + (size_t)n*kH + h5*8;
  f16x8 eC[10];
  #pragma unroll
  for (int c = 0; c < 8; ++c) eC[c] = *(const f16x8*)(erow + c*16);
  eC[8] = f8; eC[9] = xb9;

  f32x16 zero = {};
  f32x16 accP[4] = {zero, zero, zero, zero};

  // ---- P L0: triple-buffered W0 A-fragments (prefetch c+2 while MFMA'ing c)
  f16x8 wpre[3][4];
  #pragma unroll
  for (int t = 0; t < 4; ++t) wpre[0][t] = gfrag(W0d, t, lane);
  #pragma unroll
  for (int t = 0; t < 4; ++t) wpre[1][t] = gfrag(W0d, 4+t, lane);
  #pragma unroll
  for (int c = 0; c < 10; ++c) {
    if (c + 2 < 10)
      #pragma unroll
      for (int t = 0; t < 4; ++t)
        wpre[(c+2)%3][t] = gfrag(W0d, (c+2)*4 + t, lane);
    #pragma unroll
    for (int t = 0; t < 4; ++t)
      accP[t] = MFMA_(wpre[c%3][t], eC[c], accP[t], 0, 0, 0);
  }

  // L0 epilogue: batch the 16 w144 loads (one latency exposure), then the
  // select math. tangent seed = mask * w144
  float4 w4a[4][4];
  #pragma unroll
  for (int t = 0; t < 4; ++t)
    #pragma unroll
    for (int q = 0; q < 4; ++q)
      w4a[t][q] = *(const float4*)(w144buf + d*kH + t*32 + q*8 + h5*4);

  f16x8 hqP[4][2], hqT[4][2];
  #pragma unroll
  for (int t = 0; t < 4; ++t)
    #pragma unroll
    for (int q = 0; q < 4; ++q) {
      const float* wp = (const float*)&w4a[t][q];
      #pragma unroll
      for (int e = 0; e < 4; ++e) {
        float z = accP[t][q*4+e];
        bool pos = (z >= 0.f);
        hqP[t][q>>1][(q&1)*4+e] = (f16)(pos ? z : SLOPE_*z);
        hqT[t][q>>1][(q&1)*4+e] = (f16)(pos ? wp[e] : SLOPE_*wp[e]);
      }
    }
  __syncthreads();                              // B1: wbuf ready (vmcnt drain)

  // ---- L1 (LDS frags 0..35; bias via chunk 8, P only)
  f32x16 accT[4] = {zero, zero, zero, zero};
  #pragma unroll
  for (int t = 0; t < 4; ++t) accP[t] = zero;
  #pragma unroll
  for (int c = 0; c < 9; ++c) {
    f16x8 bP = (c < 8) ? hqP[c>>1][c&1] : bC;
    #pragma unroll
    for (int t = 0; t < 4; ++t) {
      f16x8 a = *(const f16x8*)(wbuf + (size_t)(c*4+t)*512 + lane*8);
      accP[t] = MFMA_(a, bP, accP[t], 0, 0, 0);
      if (c < 8) {
        f16x8 bT = hqT[c>>1][c&1];
        accT[t] = MFMA_(a, bT, accT[t], 0, 0, 0);
      }
    }
  }
  #pragma unroll
  for (int t = 0; t < 4; ++t)
    #pragma unroll
    for (int q = 0; q < 4; ++q)
      #pragma unroll
      for (int e = 0; e < 4; ++e) {
        float z = accP[t][q*4+e];
        float tv = accT[t][q*4+e];
        bool pos = (z >= 0.f);
        hqP[t][q>>1][(q&1)*4+e] = (f16)(pos ? z : SLOPE_*z);
        hqT[t][q>>1][(q&1)*4+e] = (f16)(pos ? tv : SLOPE_*tv);
      }

  // ---- L2 (LDS frags 36..71; bias via chunk 8, P only)
  #pragma unroll
  for (int t = 0; t < 4; ++t) { accP[t] = zero; accT[t] = zero; }
  #pragma unroll
  for (int c = 0; c < 9; ++c) {
    f16x8 bP = (c < 8) ? hqP[c>>1][c&1] : bC;
    #pragma unroll
    for (int t = 0; t < 4; ++t) {
      f16x8 a = *(const f16x8*)(wbuf + (size_t)(36 + c*4+t)*512 + lane*8);
      accP[t] = MFMA_(a, bP, accP[t], 0, 0, 0);
      if (c < 8) {
        f16x8 bT = hqT[c>>1][c&1];
        accT[t] = MFMA_(a, bT, accT[t], 0, 0, 0);
      }
    }
  }
  #pragma unroll
  for (int t = 0; t < 4; ++t)
    #pragma unroll
    for (int q = 0; q < 4; ++q)
      #pragma unroll
      for (int e = 0; e < 4; ++e) {
        float z = accP[t][q*4+e];
        float tv = accT[t][q*4+e];
        bool pos = (z >= 0.f);
        hqP[t][q>>1][(q&1)*4+e] = (f16)(pos ? z : SLOPE_*z);
        hqT[t][q>>1][(q&1)*4+e] = (f16)(pos ? tv : SLOPE_*tv);
      }

  // ---- final dots via MFMA (wf in output-row 0 of wfimg); preload all 8
  // WF fragments before the dependent 2-chain MFMA sequence
  f16x8 wff[8];
  #pragma unroll
  for (int c = 0; c < 8; ++c) wff[c] = gfrag(WFd, c, lane);
  accP[0] = zero; accT[0] = zero;
  #pragma unroll
  for (int c = 0; c < 8; ++c) {
    accP[0] = MFMA_(wff[c], hqP[c>>1][c&1], accP[0], 0, 0, 0);
    accT[0] = MFMA_(wff[c], hqT[c>>1][c&1], accT[0], 0, 0, 0);
  }
  // row 0 result lives in reg 0 of lanes 0..31 (col = lane)
  float llog = 0.f;
  if (!h5) {
    float p  = accP[0][0];
    float tp = accT[0][0];
    resid[(size_t)n*kD + d] = p + gbf[d];
    llog = 0.69314718055994531f * __log2f(fabsf(tp));
  }
  const int bfirst = bn / kTM;
  float s0 = (b == bfirst) ? llog : 0.f;
  float s1 = llog - s0;
  #pragma unroll
  for (int off = 32; off > 0; off >>= 1) {
    s0 += __shfl_down(s0, off, 64);
    s1 += __shfl_down(s1, off, 64);
  }
  if (lane == 0) { part[wave*2] = s0; part[wave*2 + 1] = s1; }
  __syncthreads();                              // B2
  if (tid == 0) {
    float S0 = part[0] + part[2] + part[4] + part[6];
    float S1 = part[1] + part[3] + part[5] + part[7];
    atomicAdd(&logdet[bfirst], S0);
    if (S1 != 0.f) atomicAdd(&logdet[bfirst + 1], S1);
  }
}

extern "C" void kernel_launch(void* const* d_in, const int* in_sizes, int n_in,
                              void* d_out, int out_size, void* d_ws, size_t ws_size,
                              hipStream_t stream) {
  const float* x    = (const float*)d_in[0];
  const float* emb  = (const float*)d_in[1];
  const float* fcW0 = (const float*)d_in[2];
  const float* fcb0 = (const float*)d_in[3];
  const float* fcW1 = (const float*)d_in[4];
  const float* fcb1 = (const float*)d_in[5];
  const float* fcWf = (const float*)d_in[6];
  const float* fcbf = (const float*)d_in[7];
  const float* gW0  = (const float*)d_in[8];
  const float* gb0  = (const float*)d_in[9];
  const float* gW1  = (const float*)d_in[10];
  const float* gb1  = (const float*)d_in[11];
  const float* gW2  = (const float*)d_in[12];
  const float* gb2  = (const float*)d_in[13];
  const float* gWf  = (const float*)d_in[14];
  const float* gbf  = (const float*)d_in[15];
  float* out = (float*)d_out;
  float* logdet = out + (size_t)kN * kD;

  char* ws = (char*)d_ws;
  f16*   embh    = (f16*)ws;    ws += (size_t)kN*kH*2;
  f16*   W0img   = (f16*)ws;    ws += (size_t)kD*40*512*2;
  f16*   W1img   = (f16*)ws;    ws += (size_t)kD*36*512*2;
  f16*   W2img   = (f16*)ws;    ws += (size_t)kD*36*512*2;
  f16*   wfimg   = (f16*)ws;    ws += (size_t)kD*8*512*2;
  f16*   fW0img  = (f16*)ws;    ws += (size_t)24*512*2;
  f16*   fW1img  = (f16*)ws;    ws += (size_t)32*512*2;
  f16*   fWfimg  = (f16*)ws;    ws += (size_t)32*512*2;
  float* w144buf = (float*)ws;

  cvt_kernel<<<256, 256, 0, stream>>>(gW0, gW1, gW2, gb0, gb1, gb2, gWf,
                                      fcW0, fcW1, fcWf,
                                      W0img, W1img, W2img, wfimg,
                                      fW0img, fW1img, fWfimg,
                                      w144buf, logdet);
  fc_kernel<<<kN/128, 256, 0, stream>>>(emb, fW0img, fW1img, fWfimg,
                                        fcb0, fcb1, fcbf, embh);
  g_kernel<<<dim3(kN/128, kD), 256, 0, stream>>>(
      x, embh, W0img, W1img, W2img, wfimg, w144buf, gbf, out, logdet);
}

// Round 3
// 151.885 us; speedup vs baseline: 1.0659x; 1.0387x over previous
//
#include <hip/hip_runtime.h>
#include <math.h>

typedef _Float16 f16;
typedef _Float16 f16x8 __attribute__((ext_vector_type(8)));
typedef float f32x16 __attribute__((ext_vector_type(16)));

#define MFMA_ __builtin_amdgcn_mfma_f32_32x32x16_f16
#define SLOPE_ 0.2f

constexpr int kB = 64, kT = 512, kD = 8, kH = 128, kE = 96;
constexpr int kFG = 145, kTM = 510, kN = kB * kTM;   // 32640 = 255*128
constexpr int kFCB = kN / 128;                       // 255 fc blocks

// k-permutation absorbed into weight images so next-layer B-fragments are the
// held C/D quads verbatim. For k<128 this is exactly "swap bits 2 and 3",
// hence an involution: pif(pif(k)) == k.
__device__ __forceinline__ int pif(int k) {
  if (k >= 128) return k;
  int c = k >> 4, s = (k >> 3) & 1, j = k & 7;
  return ((c >> 1) << 5) | ((c & 1) << 4) | ((j >> 2) << 3) | (s << 2) | (j & 3);
}

// fragment-linear images: frag f = 64 lanes x 16 B contiguous.
__device__ __forceinline__ f16x8 gfrag(const f16* img, int f, int lane) {
  return *(const f16x8*)(img + (size_t)f*512 + lane*8);
}

// async global->LDS DMA, 16B per lane. LDS dest = wave-uniform base + lane*16
// (linear lane-order layout required and satisfied here).
__device__ __forceinline__ void lds_dma16(const f16* g, f16* l) {
  __builtin_amdgcn_global_load_lds(
      (const __attribute__((address_space(1))) void*)g,
      (__attribute__((address_space(3))) void*)l, 16, 0, 0);
}

// ========= fc-weight pre-convert: f32 row-major -> f16 fragment-linear ======
template<int NF, int SK, int PERM>
__device__ __forceinline__ void cvt_img(const float* __restrict__ src,
                                        f16* __restrict__ dst, int nd,
                                        int t0, int stride) {
  const int per_d = NF * 512;
  for (int e = t0; e < nd * per_d; e += stride) {
    int dd = e / per_d, r = e - dd * per_d;
    int f = r >> 9, l = (r >> 3) & 63, j = r & 7;
    int c = f >> 2, t = f & 3;
    int row = t*32 + (l & 31);
    int col = c*16 + ((l >> 5) << 3) + j;
    if (PERM) col = pif(col);
    dst[e] = (f16)src[((size_t)dd*kH + row)*SK + col];
  }
}

// Small kernel: only what fc_kernel needs, plus w144/logdet init.
__global__ __launch_bounds__(256) void cvt_fc_kernel(
    const float* __restrict__ fcW0, const float* __restrict__ fcW1,
    const float* __restrict__ fcWf, const float* __restrict__ gW0,
    f16* __restrict__ fW0img, f16* __restrict__ fW1img, f16* __restrict__ fWfimg,
    float* __restrict__ w144buf, float* __restrict__ logdet)
{
  const int stride = gridDim.x * 256;
  const int t0 = blockIdx.x*256 + threadIdx.x;
  cvt_img<24, kE , 0>(fcW0, fW0img, 1, t0, stride);
  cvt_img<32, kH , 1>(fcW1, fW1img, 1, t0, stride);
  cvt_img<32, kH , 1>(fcWf, fWfimg, 1, t0, stride);
  for (int i = t0; i < kD*kH; i += stride)
    w144buf[i] = gW0[(size_t)i*kFG + 144];
  if (t0 < kB) logdet[t0] = 0.f;
}

// ===== fused dispatch: blocks 0..254 run fc_mlp; blocks 255..510 convert the
// g-weight images (source-coalesced reads, scatter 2B stores that never stall).
// The conversion rides for free under fc's MFMA latency. ==================
__global__ __launch_bounds__(256, 2) void fc_cvtg_kernel(
    const float* __restrict__ emb,
    const f16* __restrict__ fW0, const f16* __restrict__ fW1,
    const f16* __restrict__ fWf,
    const float* __restrict__ b0, const float* __restrict__ b1,
    const float* __restrict__ bf, f16* __restrict__ out,
    const float* __restrict__ gW0, const float* __restrict__ gW1,
    const float* __restrict__ gW2,
    const float* __restrict__ gb0, const float* __restrict__ gb1,
    const float* __restrict__ gb2, const float* __restrict__ gWf,
    f16* __restrict__ W0img, f16* __restrict__ W1img, f16* __restrict__ W2img,
    f16* __restrict__ wfimg)
{
  __shared__ f16 wbuf[62*512];                 // fW1 frags 0..31, fWf frags 0..29

  if (blockIdx.x >= kFCB) {
    // ---------------- cvt-g path (no LDS, no barriers) ----------------
    const int t0 = (blockIdx.x - kFCB)*256 + threadIdx.x;
    const int stride = (gridDim.x - kFCB) * 256;

    // W1/W2 main cols 0..127: source-driven. lane-consecutive colS => fully
    // coalesced f32 loads; dest col = pif(colS) (involution).
    for (int idx = t0; idx < kD*kH*kH; idx += stride) {
      int d = idx >> 14, r = idx & 16383;
      int row = r >> 7, colS = r & 127;
      float v1 = gW1[((size_t)d*kH + row)*kH + colS];
      float v2 = gW2[((size_t)d*kH + row)*kH + colS];
      int colD = pif(colS);
      int c = colD >> 4, hb = (colD >> 3) & 1, j = colD & 7;
      int e = d*36*512 + (c*4 + (row>>5))*512 + (hb*32 + (row&31))*8 + j;
      W1img[e] = (f16)v1;
      W2img[e] = (f16)v2;
    }
    // W1/W2 slab frags 32..35 (dest cols 128..143): bias at col 128, else 0.
    for (int idx = t0; idx < kD*4*512; idx += stride) {
      int d = idx >> 11, r = idx & 2047;
      int t = r >> 9, l = (r >> 3) & 63, j = r & 7;
      int hb = l >> 5, l31 = l & 31;
      int colD = 128 + hb*8 + j;
      int row = t*32 + l31;
      float v1 = (colD == 128) ? gb1[d*kH + row] : 0.f;
      float v2 = (colD == 128) ? gb2[d*kH + row] : 0.f;
      int e = d*36*512 + (32 + t)*512 + l*8 + j;
      W1img[e] = (f16)v1;
      W2img[e] = (f16)v2;
    }
    // W0 main cols 0..143: source-driven; dest col = colS<128 ? pif : colS.
    for (int idx = t0; idx < kD*kH*144; idx += stride) {
      int d = idx / (kH*144), r = idx - d*(kH*144);
      int row = r / 144, colS = r - row*144;
      float v = gW0[((size_t)d*kH + row)*kFG + colS];
      int colD = (colS < 128) ? pif(colS) : colS;
      int c = colD >> 4, hb = (colD >> 3) & 1, j = colD & 7;
      int e = d*40*512 + (c*4 + (row>>5))*512 + (hb*32 + (row&31))*8 + j;
      W0img[e] = (f16)v;
    }
    // W0 slab frags 36..39 (dest cols 144..159): w144, bias, zeros.
    for (int idx = t0; idx < kD*4*512; idx += stride) {
      int d = idx >> 11, r = idx & 2047;
      int t = r >> 9, l = (r >> 3) & 63, j = r & 7;
      int hb = l >> 5, l31 = l & 31;
      int colD = 144 + hb*8 + j;
      int row = t*32 + l31;
      float v = (colD == 144) ? gW0[((size_t)d*kH + row)*kFG + 144]
              : (colD == 145) ? gb0[d*kH + row] : 0.f;
      int e = d*40*512 + (36 + t)*512 + l*8 + j;
      W0img[e] = (f16)v;
    }
    // wfimg: 8 frags/d, wf in output-row 0 only, pi-ordered cols (tiny).
    for (int e = t0; e < kD*8*512; e += stride) {
      int dd = e >> 12, r = e & 4095;
      int f = r >> 9, l = (r >> 3) & 63, j = r & 7;
      int row = l & 31;
      int col = f*16 + ((l >> 5) << 3) + j;
      wfimg[e] = (f16)((row == 0) ? gWf[dd*kH + pif(col)] : 0.f);
    }
    return;
  }

  // ---------------- fc path (identical to previous fc_kernel) ----------------
  const int bn = blockIdx.x * 128;
  const int tid = threadIdx.x, wave = tid >> 6, lane = tid & 63;
  const int l31 = lane & 31, h5 = lane >> 5;
  const int wbase = wave << 6;
  const int n = bn + wave*32 + l31;

  // stage via LDS-DMA: no VGPR round-trip, no staging address VALU
  #pragma unroll
  for (int i = 0; i < 8; ++i)
    lds_dma16(fW1 + (size_t)(i*256 + tid)*8, wbuf + (size_t)(i*256 + wbase)*8);
  #pragma unroll
  for (int i = 0; i < 8; ++i) {
    int idx = i*256 + tid;
    if (idx < 1920)   // wave-uniform: 1920 = 7*256 + 128 (wave boundary)
      lds_dma16(fWf + (size_t)idx*8, wbuf + (size_t)(2048 + i*256 + wbase)*8);
  }

  const float* erow = emb + (size_t)n*kE + h5*8;
  f16x8 eB[6];
  #pragma unroll
  for (int c = 0; c < 6; ++c) {
    float4 a = *(const float4*)(erow + c*16);
    float4 bb = *(const float4*)(erow + c*16 + 4);
    f16x8 v;
    v[0]=(f16)a.x; v[1]=(f16)a.y; v[2]=(f16)a.z; v[3]=(f16)a.w;
    v[4]=(f16)bb.x; v[5]=(f16)bb.y; v[6]=(f16)bb.z; v[7]=(f16)bb.w;
    eB[c] = v;
  }
  __syncthreads();                              // B1: wbuf ready

  f32x16 zero = {};
  f32x16 acc[4] = {zero, zero, zero, zero};
  // triple-buffered global A-fragments: prefetch c+2 while computing c
  f16x8 wpre[3][4];
  #pragma unroll
  for (int t = 0; t < 4; ++t) wpre[0][t] = gfrag(fW0, t, lane);
  #pragma unroll
  for (int t = 0; t < 4; ++t) wpre[1][t] = gfrag(fW0, 4+t, lane);
  #pragma unroll
  for (int c = 0; c < 6; ++c) {
    if (c + 2 < 6)
      #pragma unroll
      for (int t = 0; t < 4; ++t) wpre[(c+2)%3][t] = gfrag(fW0, (c+2)*4+t, lane);
    #pragma unroll
    for (int t = 0; t < 4; ++t)
      acc[t] = MFMA_(wpre[c%3][t], eB[c], acc[t], 0, 0, 0);
  }

  f16x8 hq[4][2];
  #pragma unroll
  for (int t = 0; t < 4; ++t)
    #pragma unroll
    for (int q = 0; q < 4; ++q) {
      float4 b4 = *(const float4*)(b0 + t*32 + q*8 + h5*4);
      const float* bp = (const float*)&b4;
      #pragma unroll
      for (int e = 0; e < 4; ++e) {
        float z = acc[t][q*4+e] + bp[e];
        hq[t][q>>1][(q&1)*4+e] = (f16)fmaxf(z, SLOPE_*z);
      }
    }

  #pragma unroll
  for (int t = 0; t < 4; ++t) acc[t] = zero;
  #pragma unroll
  for (int c = 0; c < 8; ++c) {
    f16x8 bP = hq[c>>1][c&1];
    #pragma unroll
    for (int t = 0; t < 4; ++t)
      acc[t] = MFMA_(*(const f16x8*)(wbuf + (size_t)(c*4+t)*512 + lane*8),
                     bP, acc[t], 0, 0, 0);
  }
  #pragma unroll
  for (int t = 0; t < 4; ++t)
    #pragma unroll
    for (int q = 0; q < 4; ++q) {
      float4 b4 = *(const float4*)(b1 + t*32 + q*8 + h5*4);
      const float* bp = (const float*)&b4;
      #pragma unroll
      for (int e = 0; e < 4; ++e) {
        float z = acc[t][q*4+e] + bp[e];
        hq[t][q>>1][(q&1)*4+e] = (f16)fmaxf(z, SLOPE_*z);
      }
    }

  #pragma unroll
  for (int t = 0; t < 4; ++t) acc[t] = zero;
  #pragma unroll
  for (int c = 0; c < 8; ++c) {
    f16x8 bP = hq[c>>1][c&1];
    #pragma unroll
    for (int t = 0; t < 4; ++t) {
      int f = c*4 + t;
      f16x8 a = (f < 30) ? *(const f16x8*)(wbuf + (size_t)(32 + f)*512 + lane*8)
                         : gfrag(fWf, f, lane);
      acc[t] = MFMA_(a, bP, acc[t], 0, 0, 0);
    }
  }
  #pragma unroll
  for (int t = 0; t < 4; ++t)
    #pragma unroll
    for (int q = 0; q < 4; ++q) {
      float4 b4 = *(const float4*)(bf + t*32 + q*8 + h5*4);
      const float* bp = (const float*)&b4;
      #pragma unroll
      for (int e = 0; e < 4; ++e)
        hq[t][q>>1][(q&1)*4+e] = (f16)(acc[t][q*4+e] + bp[e]);
    }
  #pragma unroll
  for (int c = 0; c < 8; ++c)
    *(f16x8*)(out + (size_t)n*kH + c*16 + h5*8) = hq[c>>1][c&1];
}

// ==== g_mlp fwd + JVP: R6 structure + load pipelining (unchanged) ===========
__global__ __launch_bounds__(256, 2) void g_kernel(
    const float* __restrict__ x, const f16* __restrict__ embh,
    const f16* __restrict__ W0img, const f16* __restrict__ W1img,
    const f16* __restrict__ W2img, const f16* __restrict__ wfimg,
    const float* __restrict__ w144buf, const float* __restrict__ gbf,
    float* __restrict__ resid, float* __restrict__ logdet)
{
  __shared__ f16 wbuf[72*512];                 // W1 frags 0..35, W2 frags 36..71
  __shared__ float part[8];
  const int d = blockIdx.y, bx = blockIdx.x, bn = bx*128;
  const int tid = threadIdx.x, wave = tid >> 6, lane = tid & 63;
  const int l31 = lane & 31, h5 = lane >> 5;
  const int wbase = wave << 6;
  const int n = bn + wave*32 + l31;
  const int b = n / kTM, tt = n - b*kTM;

  const f16* W0d = W0img + (size_t)d*40*512;
  const f16* W1d = W1img + (size_t)d*36*512;
  const f16* W2d = W2img + (size_t)d*36*512;
  const f16* WFd = wfimg + (size_t)d*8*512;

  // ---- stage W1 + W2 via LDS-DMA
  #pragma unroll
  for (int i = 0; i < 9; ++i)
    lds_dma16(W1d + (size_t)(i*256 + tid)*8, wbuf + (size_t)(i*256 + wbase)*8);
  #pragma unroll
  for (int i = 0; i < 9; ++i)
    lds_dma16(W2d + (size_t)(i*256 + tid)*8,
              wbuf + (size_t)(36*512) + (size_t)(i*256 + wbase)*8);

  // x-derived inputs
  const float* xp = x + ((size_t)b*kT + tt + h5)*kD;
  float4 xa = *(const float4*)xp;
  float4 xb = *(const float4*)(xp + 4);
  f16x8 f8;
  f8[0]=(f16)xa.x; f8[1]=(f16)xa.y; f8[2]=(f16)xa.z; f8[3]=(f16)xa.w;
  f8[4]=(f16)xb.x; f8[5]=(f16)xb.y; f8[6]=(f16)xb.z; f8[7]=(f16)xb.w;
  const float xxv = x[((size_t)b*kT + tt + 2)*kD + d];
  f16x8 zeroh = {};
  f16x8 xb9 = zeroh;                 // chunk 9: [xx, 1, 0...] on h5==0 lanes
  if (!h5) { xb9[0] = (f16)xxv; xb9[1] = (f16)1.f; }
  f16x8 bC = zeroh;                  // bias chunk: [1, 0...] on h5==0 lanes
  if (!h5) bC[0] = (f16)1.f;

  // ---- preload ALL 10 B-operand chunks before the chain
  const f16* erow = embh + (size_t)n*kH + h5*8;
  f16x8 eC[10];
  #pragma unroll
  for (int c = 0; c < 8; ++c) eC[c] = *(const f16x8*)(erow + c*16);
  eC[8] = f8; eC[9] = xb9;

  f32x16 zero = {};
  f32x16 accP[4] = {zero, zero, zero, zero};

  // ---- P L0: triple-buffered W0 A-fragments (prefetch c+2 while MFMA'ing c)
  f16x8 wpre[3][4];
  #pragma unroll
  for (int t = 0; t < 4; ++t) wpre[0][t] = gfrag(W0d, t, lane);
  #pragma unroll
  for (int t = 0; t < 4; ++t) wpre[1][t] = gfrag(W0d, 4+t, lane);
  #pragma unroll
  for (int c = 0; c < 10; ++c) {
    if (c + 2 < 10)
      #pragma unroll
      for (int t = 0; t < 4; ++t)
        wpre[(c+2)%3][t] = gfrag(W0d, (c+2)*4 + t, lane);
    #pragma unroll
    for (int t = 0; t < 4; ++t)
      accP[t] = MFMA_(wpre[c%3][t], eC[c], accP[t], 0, 0, 0);
  }

  // L0 epilogue: batch the 16 w144 loads, then the select math.
  float4 w4a[4][4];
  #pragma unroll
  for (int t = 0; t < 4; ++t)
    #pragma unroll
    for (int q = 0; q < 4; ++q)
      w4a[t][q] = *(const float4*)(w144buf + d*kH + t*32 + q*8 + h5*4);

  f16x8 hqP[4][2], hqT[4][2];
  #pragma unroll
  for (int t = 0; t < 4; ++t)
    #pragma unroll
    for (int q = 0; q < 4; ++q) {
      const float* wp = (const float*)&w4a[t][q];
      #pragma unroll
      for (int e = 0; e < 4; ++e) {
        float z = accP[t][q*4+e];
        bool pos = (z >= 0.f);
        hqP[t][q>>1][(q&1)*4+e] = (f16)(pos ? z : SLOPE_*z);
        hqT[t][q>>1][(q&1)*4+e] = (f16)(pos ? wp[e] : SLOPE_*wp[e]);
      }
    }
  __syncthreads();                              // B1: wbuf ready (vmcnt drain)

  // ---- L1 (LDS frags 0..35; bias via chunk 8, P only)
  f32x16 accT[4] = {zero, zero, zero, zero};
  #pragma unroll
  for (int t = 0; t < 4; ++t) accP[t] = zero;
  #pragma unroll
  for (int c = 0; c < 9; ++c) {
    f16x8 bP = (c < 8) ? hqP[c>>1][c&1] : bC;
    #pragma unroll
    for (int t = 0; t < 4; ++t) {
      f16x8 a = *(const f16x8*)(wbuf + (size_t)(c*4+t)*512 + lane*8);
      accP[t] = MFMA_(a, bP, accP[t], 0, 0, 0);
      if (c < 8) {
        f16x8 bT = hqT[c>>1][c&1];
        accT[t] = MFMA_(a, bT, accT[t], 0, 0, 0);
      }
    }
  }
  #pragma unroll
  for (int t = 0; t < 4; ++t)
    #pragma unroll
    for (int q = 0; q < 4; ++q)
      #pragma unroll
      for (int e = 0; e < 4; ++e) {
        float z = accP[t][q*4+e];
        float tv = accT[t][q*4+e];
        bool pos = (z >= 0.f);
        hqP[t][q>>1][(q&1)*4+e] = (f16)(pos ? z : SLOPE_*z);
        hqT[t][q>>1][(q&1)*4+e] = (f16)(pos ? tv : SLOPE_*tv);
      }

  // ---- L2 (LDS frags 36..71; bias via chunk 8, P only)
  #pragma unroll
  for (int t = 0; t < 4; ++t) { accP[t] = zero; accT[t] = zero; }
  #pragma unroll
  for (int c = 0; c < 9; ++c) {
    f16x8 bP = (c < 8) ? hqP[c>>1][c&1] : bC;
    #pragma unroll
    for (int t = 0; t < 4; ++t) {
      f16x8 a = *(const f16x8*)(wbuf + (size_t)(36 + c*4+t)*512 + lane*8);
      accP[t] = MFMA_(a, bP, accP[t], 0, 0, 0);
      if (c < 8) {
        f16x8 bT = hqT[c>>1][c&1];
        accT[t] = MFMA_(a, bT, accT[t], 0, 0, 0);
      }
    }
  }
  #pragma unroll
  for (int t = 0; t < 4; ++t)
    #pragma unroll
    for (int q = 0; q < 4; ++q)
      #pragma unroll
      for (int e = 0; e < 4; ++e) {
        float z = accP[t][q*4+e];
        float tv = accT[t][q*4+e];
        bool pos = (z >= 0.f);
        hqP[t][q>>1][(q&1)*4+e] = (f16)(pos ? z : SLOPE_*z);
        hqT[t][q>>1][(q&1)*4+e] = (f16)(pos ? tv : SLOPE_*tv);
      }

  // ---- final dots via MFMA (wf in output-row 0 of wfimg)
  f16x8 wff[8];
  #pragma unroll
  for (int c = 0; c < 8; ++c) wff[c] = gfrag(WFd, c, lane);
  accP[0] = zero; accT[0] = zero;
  #pragma unroll
  for (int c = 0; c < 8; ++c) {
    accP[0] = MFMA_(wff[c], hqP[c>>1][c&1], accP[0], 0, 0, 0);
    accT[0] = MFMA_(wff[c], hqT[c>>1][c&1], accT[0], 0, 0, 0);
  }
  // row 0 result lives in reg 0 of lanes 0..31 (col = lane)
  float llog = 0.f;
  if (!h5) {
    float p  = accP[0][0];
    float tp = accT[0][0];
    resid[(size_t)n*kD + d] = p + gbf[d];
    llog = 0.69314718055994531f * __log2f(fabsf(tp));
  }
  const int bfirst = bn / kTM;
  float s0 = (b == bfirst) ? llog : 0.f;
  float s1 = llog - s0;
  #pragma unroll
  for (int off = 32; off > 0; off >>= 1) {
    s0 += __shfl_down(s0, off, 64);
    s1 += __shfl_down(s1, off, 64);
  }
  if (lane == 0) { part[wave*2] = s0; part[wave*2 + 1] = s1; }
  __syncthreads();                              // B2
  if (tid == 0) {
    float S0 = part[0] + part[2] + part[4] + part[6];
    float S1 = part[1] + part[3] + part[5] + part[7];
    atomicAdd(&logdet[bfirst], S0);
    if (S1 != 0.f) atomicAdd(&logdet[bfirst + 1], S1);
  }
}

extern "C" void kernel_launch(void* const* d_in, const int* in_sizes, int n_in,
                              void* d_out, int out_size, void* d_ws, size_t ws_size,
                              hipStream_t stream) {
  const float* x    = (const float*)d_in[0];
  const float* emb  = (const float*)d_in[1];
  const float* fcW0 = (const float*)d_in[2];
  const float* fcb0 = (const float*)d_in[3];
  const float* fcW1 = (const float*)d_in[4];
  const float* fcb1 = (const float*)d_in[5];
  const float* fcWf = (const float*)d_in[6];
  const float* fcbf = (const float*)d_in[7];
  const float* gW0  = (const float*)d_in[8];
  const float* gb0  = (const float*)d_in[9];
  const float* gW1  = (const float*)d_in[10];
  const float* gb1  = (const float*)d_in[11];
  const float* gW2  = (const float*)d_in[12];
  const float* gb2  = (const float*)d_in[13];
  const float* gWf  = (const float*)d_in[14];
  const float* gbf  = (const float*)d_in[15];
  float* out = (float*)d_out;
  float* logdet = out + (size_t)kN * kD;

  char* ws = (char*)d_ws;
  f16*   embh    = (f16*)ws;    ws += (size_t)kN*kH*2;
  f16*   W0img   = (f16*)ws;    ws += (size_t)kD*40*512*2;
  f16*   W1img   = (f16*)ws;    ws += (size_t)kD*36*512*2;
  f16*   W2img   = (f16*)ws;    ws += (size_t)kD*36*512*2;
  f16*   wfimg   = (f16*)ws;    ws += (size_t)kD*8*512*2;
  f16*   fW0img  = (f16*)ws;    ws += (size_t)24*512*2;
  f16*   fW1img  = (f16*)ws;    ws += (size_t)32*512*2;
  f16*   fWfimg  = (f16*)ws;    ws += (size_t)32*512*2;
  float* w144buf = (float*)ws;

  cvt_fc_kernel<<<256, 256, 0, stream>>>(fcW0, fcW1, fcWf, gW0,
                                         fW0img, fW1img, fWfimg,
                                         w144buf, logdet);
  fc_cvtg_kernel<<<kFCB + 256, 256, 0, stream>>>(
      emb, fW0img, fW1img, fWfimg, fcb0, fcb1, fcbf, embh,
      gW0, gW1, gW2, gb0, gb1, gb2, gWf,
      W0img, W1img, W2img, wfimg);
  g_kernel<<<dim3(kN/128, kD), 256, 0, stream>>>(
      x, embh, W0img, W1img, W2img, wfimg, w144buf, gbf, out, logdet);
}